// Round 2
// baseline (510.168 us; speedup 1.0000x reference)
//
#include <hip/hip_runtime.h>
#include <hip/hip_bf16.h>

#define B_ 8
#define T_ 4096
#define D_ 512
#define L_ 128
#define H_ 8
#define Dh_ 64
#define Lh_ 16
#define M_ (B_*T_)          // 32768 rows
#define SCALE 0.125f        // rsqrt(Dh)

typedef __bf16 v8bf __attribute__((ext_vector_type(8)));
typedef float  v4f  __attribute__((ext_vector_type(4)));
typedef unsigned short u16;
typedef u16 v8u __attribute__((ext_vector_type(8)));

__device__ __forceinline__ float b2f(u16 h){
    unsigned int u = ((unsigned int)h) << 16;
    return __builtin_bit_cast(float, u);
}
__device__ __forceinline__ u16 f2bf(float f){
    unsigned int u = __builtin_bit_cast(unsigned int, f);
    u += 0x7FFFu + ((u >> 16) & 1u);   // RNE
    return (u16)(u >> 16);
}

// ---------------------------------------------------------------------------
// P-1: fp32 -> bf16 bulk convert (X).  8 elems / thread.
// ---------------------------------------------------------------------------
__global__ __launch_bounds__(256) void f32_to_bf16(
        const float* __restrict__ src, u16* __restrict__ dst)
{
    const size_t i = (size_t)blockIdx.x * 256 + threadIdx.x;  // i-th group of 8
    const float4* s = (const float4*)src + i * 2;
    float4 a = s[0], b = s[1];
    v8u o;
    o[0] = f2bf(a.x); o[1] = f2bf(a.y); o[2] = f2bf(a.z); o[3] = f2bf(a.w);
    o[4] = f2bf(b.x); o[5] = f2bf(b.y); o[6] = f2bf(b.z); o[7] = f2bf(b.w);
    *((v8u*)dst + i) = o;
}

// ---------------------------------------------------------------------------
// P0: weight transpose, fp32 src (rows x cols) -> bf16 dst (cols x rows)
// ---------------------------------------------------------------------------
__global__ __launch_bounds__(256) void transpose_w(
        const float* __restrict__ src, u16* __restrict__ dst, int rows, int cols)
{
    __shared__ u16 tile[32][33];
    int tx = threadIdx.x, ty = threadIdx.y;          // (32,8)
    int c0 = blockIdx.x * 32, r0 = blockIdx.y * 32;
    #pragma unroll
    for (int i = 0; i < 32; i += 8)
        tile[ty + i][tx] = f2bf(src[(size_t)(r0 + ty + i) * cols + c0 + tx]);
    __syncthreads();
    #pragma unroll
    for (int i = 0; i < 32; i += 8)
        dst[(size_t)(c0 + ty + i) * rows + r0 + tx] = tile[tx][ty + i];
}

// ---------------------------------------------------------------------------
// P1/P5: MFMA bf16 GEMM.  A (Mx512) row-major bf16, Bt (Nx512) row-major bf16
// (pre-transposed weights).  MODE 0: write Q(f32) / KE=exp(K*s)(f32) / V(bf16)
// by column region.  MODE 1: write fp32 Out (Mx512).
// ---------------------------------------------------------------------------
template<int MODE>
__global__ __launch_bounds__(256) void gemm_mfma(
        const u16* __restrict__ A, const u16* __restrict__ Bt,
        float* __restrict__ Qo, float* __restrict__ KEo,
        u16* __restrict__ Vo, float* __restrict__ OutF)
{
    __shared__ __align__(16) u16 As[128][48];   // 96B rows, 16B-aligned
    __shared__ __align__(16) u16 Bs[128][48];
    const int tid  = threadIdx.x;
    const int wave = tid >> 6, lane = tid & 63;
    const int wm = wave >> 1, wn = wave & 1;     // 2x2 waves, 64x64 each
    const int lm = lane & 15, quad = lane >> 4;
    const int gm0 = blockIdx.x * 128, gn0 = blockIdx.y * 128;

    v4f acc[4][4];
    #pragma unroll
    for (int i = 0; i < 4; i++)
        #pragma unroll
        for (int j = 0; j < 4; j++)
            acc[i][j] = (v4f){0.f, 0.f, 0.f, 0.f};

    for (int kt = 0; kt < 16; ++kt) {
        const int k0 = kt * 32;
        #pragma unroll
        for (int rep = 0; rep < 2; ++rep) {
            int lin = tid + rep * 256;           // 0..511
            int r = lin >> 2, c8 = (lin & 3) * 8;
            *(v8u*)&As[r][c8] = *(const v8u*)&A [(size_t)(gm0 + r) * 512 + k0 + c8];
            *(v8u*)&Bs[r][c8] = *(const v8u*)&Bt[(size_t)(gn0 + r) * 512 + k0 + c8];
        }
        __syncthreads();
        v8bf af[4], bfr[4];
        #pragma unroll
        for (int mi = 0; mi < 4; mi++)
            af[mi] = *(const v8bf*)&As[wm * 64 + mi * 16 + lm][quad * 8];
        #pragma unroll
        for (int ni = 0; ni < 4; ni++)
            bfr[ni] = *(const v8bf*)&Bs[wn * 64 + ni * 16 + lm][quad * 8];
        #pragma unroll
        for (int mi = 0; mi < 4; mi++)
            #pragma unroll
            for (int ni = 0; ni < 4; ni++)
                acc[mi][ni] = __builtin_amdgcn_mfma_f32_16x16x32_bf16(
                                  af[mi], bfr[ni], acc[mi][ni], 0, 0, 0);
        __syncthreads();
    }

    #pragma unroll
    for (int mi = 0; mi < 4; mi++)
      #pragma unroll
      for (int ni = 0; ni < 4; ni++)
        #pragma unroll
        for (int i = 0; i < 4; i++) {
            int row = gm0 + wm * 64 + mi * 16 + quad * 4 + i;  // C/D: row=quad*4+reg
            int col = gn0 + wn * 64 + ni * 16 + lm;            //      col=lane&15
            float v = acc[mi][ni][i];
            if (MODE == 0) {
                if (col < 128)        Qo [(size_t)row * 128 + col]       = v;
                else if (col < 256)   KEo[(size_t)row * 128 + col - 128] = __expf(v * SCALE);
                else                  Vo [(size_t)row * 512 + col - 256] = f2bf(v);
            } else {
                OutF[(size_t)row * 512 + col] = v;
            }
        }
}

// ---------------------------------------------------------------------------
// P2a: per (b,h,chunk): M_c[l][d] = sum_t ke[t][l]*v[t][d];  lsum[l]=sum_t ke
// blockIdx.x = bh*64 + c;  64 threads (thread = d)
// ---------------------------------------------------------------------------
__global__ __launch_bounds__(64) void chunk_sums(
        const float* __restrict__ KE, const u16* __restrict__ V,
        float* __restrict__ Mc, float* __restrict__ AB)
{
    __shared__ float ske[64][17];
    const int blk = blockIdx.x;
    const int bh = blk >> 6, c = blk & 63;
    const int b = bh >> 3, h = bh & 7;
    const int t0 = b * T_ + c * 64;
    const int tid = threadIdx.x;

    #pragma unroll
    for (int rep = 0; rep < 16; ++rep) {
        int idx = rep * 64 + tid;
        int tt = idx >> 4, l = idx & 15;
        ske[tt][l] = KE[(size_t)(t0 + tt) * L_ + h * Lh_ + l];
    }
    __syncthreads();

    float macc[16];
    #pragma unroll
    for (int l = 0; l < 16; l++) macc[l] = 0.f;
    const int d = tid;
    for (int t = 0; t < 64; ++t) {
        float v = b2f(V[(size_t)(t0 + t) * D_ + h * Dh_ + d]);
        #pragma unroll
        for (int l = 0; l < 16; l++) macc[l] += ske[t][l] * v;
    }
    float* mcb = Mc + (size_t)blk * 1024;
    #pragma unroll
    for (int l = 0; l < 16; l++) mcb[l * 64 + d] = macc[l];

    if (tid < 16) {
        float s = 0.f;
        for (int t = 0; t < 64; ++t) s += ske[t][tid];
        AB[blk * 16 + tid] = s;
    }
}

// ---------------------------------------------------------------------------
// P2b: exclusive prefix over chunks (in-place).  64 blocks (bh), 1024 threads.
// ---------------------------------------------------------------------------
__global__ __launch_bounds__(1024) void chunk_prefix(
        float* __restrict__ Mc, float* __restrict__ AB)
{
    const int bh = blockIdx.x, i = threadIdx.x;
    float run = 0.f;
    for (int c = 0; c < 64; ++c) {
        size_t off = ((size_t)(bh * 64 + c)) * 1024 + i;
        float m = Mc[off]; Mc[off] = run; run += m;
    }
    if (i < 16) {
        float run2 = 0.f;
        for (int c = 0; c < 64; ++c) {
            int off = (bh * 64 + c) * 16 + i;
            float a = AB[off]; AB[off] = run2; run2 += a;
        }
    }
}

// ---------------------------------------------------------------------------
// P3: per (b,h,chunk): alpha cumsum, softmax, y = qs*S_c + (qs.ke^T masked)*V
// 64 threads (thread = t within chunk).  Writes Y in (T, B*H, Dh) layout.
// ---------------------------------------------------------------------------
__global__ __launch_bounds__(64) void intra_chunk(
        const float* __restrict__ Q, const float* __restrict__ KE,
        const u16* __restrict__ V, const float* __restrict__ Mc,
        const float* __restrict__ AB, u16* __restrict__ Y)
{
    __shared__ float ske[64][17];
    __shared__ float sv [64][65];
    __shared__ float sS [16][65];
    const int blk = blockIdx.x;
    const int bh = blk >> 6, c = blk & 63;
    const int b = bh >> 3, h = bh & 7;
    const int t0 = b * T_ + c * 64;
    const int t = threadIdx.x;

    #pragma unroll
    for (int rep = 0; rep < 16; ++rep) {
        int idx = rep * 64 + t;
        int tt = idx >> 4, l = idx & 15;
        ske[tt][l] = KE[(size_t)(t0 + tt) * L_ + h * Lh_ + l];
    }
    {   // V row t -> LDS (vectorized 16B loads)
        const u16* vp = V + (size_t)(t0 + t) * D_ + h * Dh_;
        #pragma unroll
        for (int seg = 0; seg < 8; ++seg) {
            v8u pv = *(const v8u*)(vp + seg * 8);
            #pragma unroll
            for (int j = 0; j < 8; j++) sv[t][seg * 8 + j] = b2f(pv[j]);
        }
    }
    {   // chunk-start state S_c
        const float* mcb = Mc + (size_t)blk * 1024;
        #pragma unroll
        for (int j = 0; j < 16; ++j) sS[j][t] = mcb[j * 64 + t];
    }
    __syncthreads();

    // inclusive alpha at own t
    float alpha[16];
    #pragma unroll
    for (int l = 0; l < 16; l++) alpha[l] = AB[blk * 16 + l];
    for (int tp = 0; tp < 64; ++tp) {
        bool pr = (tp <= t);
        #pragma unroll
        for (int l = 0; l < 16; l++) { float kv = ske[tp][l]; if (pr) alpha[l] += kv; }
    }

    // qs = softmax(q*scale) / alpha
    float q[16], mx = -1e30f;
    const float* qp = Q + (size_t)(t0 + t) * L_ + h * Lh_;
    #pragma unroll
    for (int seg = 0; seg < 4; ++seg) {
        float4 qq = *(const float4*)(qp + seg * 4);
        q[seg*4+0] = qq.x * SCALE; q[seg*4+1] = qq.y * SCALE;
        q[seg*4+2] = qq.z * SCALE; q[seg*4+3] = qq.w * SCALE;
    }
    #pragma unroll
    for (int l = 0; l < 16; l++) mx = fmaxf(mx, q[l]);
    float s = 0.f;
    #pragma unroll
    for (int l = 0; l < 16; l++) { q[l] = __expf(q[l] - mx); s += q[l]; }
    const float inv = 1.f / s;
    float qs[16];
    #pragma unroll
    for (int l = 0; l < 16; l++) qs[l] = q[l] * inv / alpha[l];

    // y = qs . S_c  +  sum_{tp<=t} (qs.ke_tp) * v_tp
    float y[64];
    #pragma unroll
    for (int d = 0; d < 64; d++) y[d] = 0.f;
    #pragma unroll
    for (int l = 0; l < 16; l++) {
        float w = qs[l];
        #pragma unroll
        for (int d = 0; d < 64; d++) y[d] += w * sS[l][d];
    }
    for (int tp = 0; tp < 64; ++tp) {
        float p = 0.f;
        #pragma unroll
        for (int l = 0; l < 16; l++) p += qs[l] * ske[tp][l];
        if (tp <= t) {
            #pragma unroll
            for (int d = 0; d < 64; d++) y[d] += p * sv[tp][d];
        }
    }

    // Y layout: flat = tg*4096 + bh*64 + dh
    u16* yp = Y + ((size_t)(c * 64 + t) * 64 + bh) * 64;
    #pragma unroll
    for (int seg = 0; seg < 8; ++seg) {
        v8u pk;
        #pragma unroll
        for (int j = 0; j < 8; j++) pk[j] = f2bf(y[seg * 8 + j]);
        *(v8u*)(yp + seg * 8) = pk;
    }
}

// ---------------------------------------------------------------------------
// P4: Z = Y^T :  Y (262144 x 64)  ->  Z (64 x 262144)
// reference's transpose(3,0,1,2).reshape(B,T,D) == this transpose:
//   Z_flat = dh*262144 + t*64 + b*8 + h
// ---------------------------------------------------------------------------
__global__ __launch_bounds__(64) void transpose_Y(
        const u16* __restrict__ Y, u16* __restrict__ Z)
{
    __shared__ __align__(16) u16 tile[64][72];
    const int g = blockIdx.x;        // 64-row group of Y
    const int t = threadIdx.x;
    const u16* yp = Y + ((size_t)(g * 64 + t)) * 64;
    #pragma unroll
    for (int seg = 0; seg < 8; ++seg)
        *(v8u*)&tile[t][seg * 8] = *(const v8u*)(yp + seg * 8);
    __syncthreads();
    const int d = t;
    u16* zp = Z + (size_t)d * 262144 + (size_t)g * 64;
    #pragma unroll
    for (int seg = 0; seg < 8; ++seg) {
        v8u pk;
        #pragma unroll
        for (int j = 0; j < 8; j++) pk[j] = tile[seg * 8 + j][d];
        *(v8u*)(zp + seg * 8) = pk;
    }
}

// ---------------------------------------------------------------------------
extern "C" void kernel_launch(void* const* d_in, const int* in_sizes, int n_in,
                              void* d_out, int out_size, void* d_ws, size_t ws_size,
                              hipStream_t stream)
{
    (void)in_sizes; (void)n_in; (void)out_size; (void)ws_size;
    // Reference dtypes are float32 throughout.
    const float* X  = (const float*)d_in[0];
    const float* Wk = (const float*)d_in[1];   // dict order: X, Wk, Wq, Wv, o_proj
    const float* Wq = (const float*)d_in[2];
    const float* Wv = (const float*)d_in[3];
    const float* Wo = (const float*)d_in[4];
    float* Out = (float*)d_out;

    char* p = (char*)d_ws;
    auto alloc = [&](size_t bytes) { char* r = p; p += (bytes + 255) & ~(size_t)255; return r; };
    u16*   Xb = (u16*)  alloc((size_t)M_ * 512 * 2);    // X in bf16
    u16*   WT = (u16*)  alloc((size_t)768 * 512 * 2);   // [Wq^T | Wk^T | Wv^T] bf16
    u16*   OT = (u16*)  alloc((size_t)512 * 512 * 2);   // o_proj^T bf16
    u16*   V  = (u16*)  alloc((size_t)M_ * 512 * 2);
    float* Mc = (float*)alloc((size_t)4096 * 1024 * 4); // chunk states
    float* AB = (float*)alloc((size_t)4096 * 16 * 4);   // alpha chunk bases
    float* Q  = (float*)alloc((size_t)M_ * 128 * 4);
    float* KE = (float*)alloc((size_t)M_ * 128 * 4);
    u16*   Y  = (u16*)  alloc((size_t)M_ * 512 * 2);
    u16*   Z  = (u16*)Q;   // alias: Q+KE (33.5MB contiguous) dead after P3

    f32_to_bf16<<<8192, 256, 0, stream>>>(X, Xb);       // 16.7M elems / 8 per thread

    dim3 tb(32, 8);
    transpose_w<<<dim3(4, 16),  tb, 0, stream>>>(Wq, WT + 0   * 512, 512, 128);
    transpose_w<<<dim3(4, 16),  tb, 0, stream>>>(Wk, WT + 128 * 512, 512, 128);
    transpose_w<<<dim3(16, 16), tb, 0, stream>>>(Wv, WT + 256 * 512, 512, 512);
    transpose_w<<<dim3(16, 16), tb, 0, stream>>>(Wo, OT,             512, 512);

    gemm_mfma<0><<<dim3(256, 6), 256, 0, stream>>>(Xb, WT, Q, KE, V, nullptr);
    chunk_sums  <<<4096, 64,   0, stream>>>(KE, V, Mc, AB);
    chunk_prefix<<<64,   1024, 0, stream>>>(Mc, AB);
    intra_chunk <<<4096, 64,   0, stream>>>(Q, KE, V, Mc, AB, Y);
    transpose_Y <<<4096, 64,   0, stream>>>(Y, Z);
    gemm_mfma<1><<<dim3(256, 4), 256, 0, stream>>>(Z, OT, nullptr, nullptr, nullptr, Out);
}

// Round 3
// 285.533 us; speedup vs baseline: 1.7867x; 1.7867x over previous
//
#include <hip/hip_runtime.h>
#include <hip/hip_bf16.h>

#define B_ 8
#define T_ 4096
#define D_ 512
#define L_ 128
#define H_ 8
#define Dh_ 64
#define Lh_ 16
#define M_ (B_*T_)          // 32768 rows
#define SCALE 0.125f        // rsqrt(Dh)

typedef __bf16 v8bf __attribute__((ext_vector_type(8)));
typedef float  v4f  __attribute__((ext_vector_type(4)));
typedef unsigned short u16;
typedef u16 v8u __attribute__((ext_vector_type(8)));

__device__ __forceinline__ float b2f(u16 h){
    unsigned int u = ((unsigned int)h) << 16;
    return __builtin_bit_cast(float, u);
}
__device__ __forceinline__ u16 f2bf(float f){
    unsigned int u = __builtin_bit_cast(unsigned int, f);
    u += 0x7FFFu + ((u >> 16) & 1u);   // RNE
    return (u16)(u >> 16);
}

// ---------------------------------------------------------------------------
// P-1: fp32 -> bf16 bulk convert (X).  8 elems / thread.
// ---------------------------------------------------------------------------
__global__ __launch_bounds__(256) void f32_to_bf16(
        const float* __restrict__ src, u16* __restrict__ dst)
{
    const size_t i = (size_t)blockIdx.x * 256 + threadIdx.x;
    const float4* s = (const float4*)src + i * 2;
    float4 a = s[0], b = s[1];
    v8u o;
    o[0] = f2bf(a.x); o[1] = f2bf(a.y); o[2] = f2bf(a.z); o[3] = f2bf(a.w);
    o[4] = f2bf(b.x); o[5] = f2bf(b.y); o[6] = f2bf(b.z); o[7] = f2bf(b.w);
    *((v8u*)dst + i) = o;
}

// ---------------------------------------------------------------------------
// P0: weight transpose, fp32 src (rows x cols) -> bf16 dst (cols x rows)
// ---------------------------------------------------------------------------
__global__ __launch_bounds__(256) void transpose_w(
        const float* __restrict__ src, u16* __restrict__ dst, int rows, int cols)
{
    __shared__ u16 tile[32][33];
    int tx = threadIdx.x, ty = threadIdx.y;          // (32,8)
    int c0 = blockIdx.x * 32, r0 = blockIdx.y * 32;
    #pragma unroll
    for (int i = 0; i < 32; i += 8)
        tile[ty + i][tx] = f2bf(src[(size_t)(r0 + ty + i) * cols + c0 + tx]);
    __syncthreads();
    #pragma unroll
    for (int i = 0; i < 32; i += 8)
        dst[(size_t)(c0 + ty + i) * rows + r0 + tx] = tile[tx][ty + i];
}

// ---------------------------------------------------------------------------
// P1/P5: MFMA bf16 GEMM.  MODE 0: write Q(f32) / KE=exp(K*s)(bf16) / V(bf16).
// MODE 1: write fp32 Out.
// ---------------------------------------------------------------------------
template<int MODE>
__global__ __launch_bounds__(256) void gemm_mfma(
        const u16* __restrict__ A, const u16* __restrict__ Bt,
        float* __restrict__ Qo, u16* __restrict__ KEo,
        u16* __restrict__ Vo, float* __restrict__ OutF)
{
    __shared__ __align__(16) u16 As[128][48];
    __shared__ __align__(16) u16 Bs[128][48];
    const int tid  = threadIdx.x;
    const int wave = tid >> 6, lane = tid & 63;
    const int wm = wave >> 1, wn = wave & 1;
    const int lm = lane & 15, quad = lane >> 4;
    const int gm0 = blockIdx.x * 128, gn0 = blockIdx.y * 128;

    v4f acc[4][4];
    #pragma unroll
    for (int i = 0; i < 4; i++)
        #pragma unroll
        for (int j = 0; j < 4; j++)
            acc[i][j] = (v4f){0.f, 0.f, 0.f, 0.f};

    for (int kt = 0; kt < 16; ++kt) {
        const int k0 = kt * 32;
        #pragma unroll
        for (int rep = 0; rep < 2; ++rep) {
            int lin = tid + rep * 256;
            int r = lin >> 2, c8 = (lin & 3) * 8;
            *(v8u*)&As[r][c8] = *(const v8u*)&A [(size_t)(gm0 + r) * 512 + k0 + c8];
            *(v8u*)&Bs[r][c8] = *(const v8u*)&Bt[(size_t)(gn0 + r) * 512 + k0 + c8];
        }
        __syncthreads();
        v8bf af[4], bfr[4];
        #pragma unroll
        for (int mi = 0; mi < 4; mi++)
            af[mi] = *(const v8bf*)&As[wm * 64 + mi * 16 + lm][quad * 8];
        #pragma unroll
        for (int ni = 0; ni < 4; ni++)
            bfr[ni] = *(const v8bf*)&Bs[wn * 64 + ni * 16 + lm][quad * 8];
        #pragma unroll
        for (int mi = 0; mi < 4; mi++)
            #pragma unroll
            for (int ni = 0; ni < 4; ni++)
                acc[mi][ni] = __builtin_amdgcn_mfma_f32_16x16x32_bf16(
                                  af[mi], bfr[ni], acc[mi][ni], 0, 0, 0);
        __syncthreads();
    }

    #pragma unroll
    for (int mi = 0; mi < 4; mi++)
      #pragma unroll
      for (int ni = 0; ni < 4; ni++)
        #pragma unroll
        for (int i = 0; i < 4; i++) {
            int row = gm0 + wm * 64 + mi * 16 + quad * 4 + i;
            int col = gn0 + wn * 64 + ni * 16 + lm;
            float v = acc[mi][ni][i];
            if (MODE == 0) {
                if (col < 128)        Qo [(size_t)row * 128 + col]       = v;
                else if (col < 256)   KEo[(size_t)row * 128 + col - 128] = f2bf(__expf(v * SCALE));
                else                  Vo [(size_t)row * 512 + col - 256] = f2bf(v);
            } else {
                OutF[(size_t)row * 512 + col] = v;
            }
        }
}

// ---------------------------------------------------------------------------
// P2a (MFMA): per chunk, one wave: M_c = KE^T(16x64) . V(64x64), lsum = KE^T . 1
// 4 chunks / 256-thread block.  KA[l][tp], VT[d][tp] bf16 staging.
// ---------------------------------------------------------------------------
__global__ __launch_bounds__(256, 2) void chunk_sums_mfma(
        const u16* __restrict__ KE, const u16* __restrict__ V,
        float* __restrict__ Mc, float* __restrict__ AB)
{
    struct CLDS { u16 KA[16][72]; u16 VT[64][72]; };
    __shared__ __align__(16) CLDS lds[4];
    const int tid = threadIdx.x, wave = tid >> 6, lane = tid & 63;
    const int lm = lane & 15, quad = lane >> 4;
    const int ch = blockIdx.x * 4 + wave;             // chunk id 0..4095
    const int bh = ch >> 6, c = ch & 63, b = bh >> 3, h = bh & 7;
    const int t0 = b * T_ + c * 64;
    CLDS& L = lds[wave];

    {   // stage KE row (tp = lane) -> KA[l][lane];  V row -> VT[d][lane]
        const u16* kp = KE + (size_t)(t0 + lane) * L_ + h * Lh_;
        v8u k0 = *(const v8u*)kp, k1 = *(const v8u*)(kp + 8);
        #pragma unroll
        for (int l = 0; l < 8; l++) L.KA[l][lane]     = k0[l];
        #pragma unroll
        for (int l = 0; l < 8; l++) L.KA[l + 8][lane] = k1[l];
        const u16* vp = V + (size_t)(t0 + lane) * D_ + h * Dh_;
        #pragma unroll
        for (int seg = 0; seg < 8; ++seg) {
            v8u pv = *(const v8u*)(vp + seg * 8);
            #pragma unroll
            for (int j = 0; j < 8; j++) L.VT[seg * 8 + j][lane] = pv[j];
        }
    }
    __syncthreads();

    v8bf ka[2];
    #pragma unroll
    for (int ki = 0; ki < 2; ki++)
        ka[ki] = *(const v8bf*)&L.KA[lm][ki * 32 + quad * 8];

    v8u onesu;
    #pragma unroll
    for (int j = 0; j < 8; j++) onesu[j] = 0x3F80;
    v8bf ones = __builtin_bit_cast(v8bf, onesu);

    v4f accL = (v4f){0.f, 0.f, 0.f, 0.f};
    accL = __builtin_amdgcn_mfma_f32_16x16x32_bf16(ka[0], ones, accL, 0, 0, 0);
    accL = __builtin_amdgcn_mfma_f32_16x16x32_bf16(ka[1], ones, accL, 0, 0, 0);

    v4f accM[4];
    #pragma unroll
    for (int nd = 0; nd < 4; nd++) accM[nd] = (v4f){0.f, 0.f, 0.f, 0.f};
    #pragma unroll
    for (int nd = 0; nd < 4; nd++)
        #pragma unroll
        for (int ki = 0; ki < 2; ki++) {
            v8bf vb = *(const v8bf*)&L.VT[nd * 16 + lm][ki * 32 + quad * 8];
            accM[nd] = __builtin_amdgcn_mfma_f32_16x16x32_bf16(ka[ki], vb, accM[nd], 0, 0, 0);
        }

    float* mcb = Mc + (size_t)ch * 1024;   // [l][d], row l = quad*4+i, col d = nd*16+lm
    #pragma unroll
    for (int nd = 0; nd < 4; nd++)
        #pragma unroll
        for (int i = 0; i < 4; i++)
            mcb[(quad * 4 + i) * 64 + nd * 16 + lm] = accM[nd][i];
    if (lm == 0) {
        #pragma unroll
        for (int i = 0; i < 4; i++) AB[ch * 16 + quad * 4 + i] = accL[i];
    }
}

// ---------------------------------------------------------------------------
// P2b: exclusive prefix over chunks (in-place).  256 blocks x 256 threads.
// ---------------------------------------------------------------------------
__global__ __launch_bounds__(256) void chunk_prefix(
        float* __restrict__ Mc, float* __restrict__ AB)
{
    const int bh = blockIdx.x >> 2, qq = blockIdx.x & 3;
    const int i = qq * 256 + threadIdx.x;
    float run = 0.f;
    for (int c = 0; c < 64; ++c) {
        size_t off = ((size_t)(bh * 64 + c)) * 1024 + i;
        float m = Mc[off]; Mc[off] = run; run += m;
    }
    if (qq == 0 && threadIdx.x < 16) {
        float r2 = 0.f; const int l = threadIdx.x;
        for (int c = 0; c < 64; ++c) {
            int off = (bh * 64 + c) * 16 + l;
            float a = AB[off]; AB[off] = r2; r2 += a;
        }
    }
}

// ---------------------------------------------------------------------------
// P3 (MFMA): per chunk, one wave:
//   alpha = AB + TrilOnes(64x64).KE(64x16)          (tril A-frag in registers)
//   qs = softmax(q*s)/alpha  (shuffle row-reduce in C-layout)
//   P  = QS(64x16,pad32).KE^T   masked lower-tri    (LDS round-trip C->A)
//   Y  = QS.S_c + P.V
// 4 chunks / 256-thread block; p aliases dead {KA,Sc,qs}.
// ---------------------------------------------------------------------------
__global__ __launch_bounds__(256, 2) void intra_mfma(
        const float* __restrict__ Q, const u16* __restrict__ KE,
        const u16* __restrict__ V, const float* __restrict__ Mc,
        const float* __restrict__ AB, u16* __restrict__ Y)
{
    struct ILDS {
        union {
            struct { u16 KA[16][72]; u16 Sc[16][72]; u16 qs[64][40]; } s;
            u16 p[64][72];
        } r;
        u16 VT[64][72];
    };
    __shared__ __align__(16) ILDS lds[4];
    const int tid = threadIdx.x, wave = tid >> 6, lane = tid & 63;
    const int lm = lane & 15, quad = lane >> 4;
    const int ch = blockIdx.x * 4 + wave;
    const int bh = ch >> 6, c = ch & 63, b = bh >> 3, h = bh & 7;
    const int t0 = b * T_ + c * 64;
    ILDS& L = lds[wave];

    {   // staging (lane = tp / d-row)
        const u16* kp = KE + (size_t)(t0 + lane) * L_ + h * Lh_;
        v8u k0 = *(const v8u*)kp, k1 = *(const v8u*)(kp + 8);
        #pragma unroll
        for (int l = 0; l < 8; l++) L.r.s.KA[l][lane]     = k0[l];
        #pragma unroll
        for (int l = 0; l < 8; l++) L.r.s.KA[l + 8][lane] = k1[l];
        const u16* vp = V + (size_t)(t0 + lane) * D_ + h * Dh_;
        #pragma unroll
        for (int seg = 0; seg < 8; ++seg) {
            v8u pv = *(const v8u*)(vp + seg * 8);
            #pragma unroll
            for (int j = 0; j < 8; j++) L.VT[seg * 8 + j][lane] = pv[j];
        }
        const float* mcb = Mc + (size_t)ch * 1024;
        #pragma unroll
        for (int l = 0; l < 16; l++)
            L.r.s.Sc[l][lane] = f2bf(mcb[l * 64 + lane]);
        v8u z8;
        #pragma unroll
        for (int j = 0; j < 8; j++) z8[j] = 0;
        *(v8u*)&L.r.s.qs[lane][16] = z8;     // zero K-pad cols 16..31
        *(v8u*)&L.r.s.qs[lane][24] = z8;
    }
    const float ab = AB[ch * 16 + lm];
    __syncthreads();

    // ---- alpha = AB + tril . ke ----
    v4f acc_a[4];
    #pragma unroll
    for (int mi = 0; mi < 4; mi++) acc_a[mi] = (v4f){ab, ab, ab, ab};
    #pragma unroll
    for (int mi = 0; mi < 4; mi++)
        #pragma unroll
        for (int ki = 0; ki < 2; ki++) {
            if (ki == 1 && mi < 2) continue;        // tp >= 32 > t: zero block
            v8u ta;
            #pragma unroll
            for (int j = 0; j < 8; j++)
                ta[j] = (ki * 32 + quad * 8 + j <= mi * 16 + lm) ? (u16)0x3F80 : (u16)0;
            v8bf kb = *(const v8bf*)&L.r.s.KA[lm][ki * 32 + quad * 8];
            acc_a[mi] = __builtin_amdgcn_mfma_f32_16x16x32_bf16(
                            __builtin_bit_cast(v8bf, ta), kb, acc_a[mi], 0, 0, 0);
        }

    // ---- qs = softmax(q*s)/alpha, write to qs_lds in A-layout ----
    #pragma unroll
    for (int mi = 0; mi < 4; mi++)
        #pragma unroll
        for (int i = 0; i < 4; i++) {
            int t = mi * 16 + quad * 4 + i;
            float qv = Q[(size_t)(t0 + t) * L_ + h * Lh_ + lm] * SCALE;
            float m = qv;
            #pragma unroll
            for (int off = 1; off < 16; off <<= 1) m = fmaxf(m, __shfl_xor(m, off));
            float e = __expf(qv - m);
            float s = e;
            #pragma unroll
            for (int off = 1; off < 16; off <<= 1) s += __shfl_xor(s, off);
            L.r.s.qs[t][lm] = f2bf(e / (s * acc_a[mi][i]));
        }
    __syncthreads();

    // ---- A-frags of qs; P-MFMA (lower tiles); Y(a) = QS . S_c ----
    v8bf aq[4];
    #pragma unroll
    for (int mi = 0; mi < 4; mi++)
        aq[mi] = *(const v8bf*)&L.r.s.qs[mi * 16 + lm][quad * 8];

    v4f accP[4][4], accY[4][4];
    #pragma unroll
    for (int mi = 0; mi < 4; mi++)
        #pragma unroll
        for (int ni = 0; ni < 4; ni++) {
            accP[mi][ni] = (v4f){0.f, 0.f, 0.f, 0.f};
            accY[mi][ni] = (v4f){0.f, 0.f, 0.f, 0.f};
        }

    #pragma unroll
    for (int ni = 0; ni < 4; ni++) {
        v8u kbu;                                   // B-frag: ke[tp=ni*16+lm][l=quad*8+j]
        #pragma unroll
        for (int j = 0; j < 8; j++) kbu[j] = 0;
        if (quad < 2) {
            #pragma unroll
            for (int j = 0; j < 8; j++)
                kbu[j] = L.r.s.KA[quad * 8 + j][ni * 16 + lm];
        }
        v8bf kbf = __builtin_bit_cast(v8bf, kbu);
        #pragma unroll
        for (int mi = ni; mi < 4; mi++)
            accP[mi][ni] = __builtin_amdgcn_mfma_f32_16x16x32_bf16(
                               aq[mi], kbf, accP[mi][ni], 0, 0, 0);
    }
    #pragma unroll
    for (int nd = 0; nd < 4; nd++) {
        v8u scu;                                   // B-frag: Sc[l=quad*8+j][d=nd*16+lm]
        #pragma unroll
        for (int j = 0; j < 8; j++) scu[j] = 0;
        if (quad < 2) {
            #pragma unroll
            for (int j = 0; j < 8; j++)
                scu[j] = L.r.s.Sc[quad * 8 + j][nd * 16 + lm];
        }
        v8bf scf = __builtin_bit_cast(v8bf, scu);
        #pragma unroll
        for (int mi = 0; mi < 4; mi++)
            accY[mi][nd] = __builtin_amdgcn_mfma_f32_16x16x32_bf16(
                               aq[mi], scf, accY[mi][nd], 0, 0, 0);
    }
    __syncthreads();                               // all reads of r.s done

    // ---- write masked P (bf16) over dead KA/Sc/qs ----
    #pragma unroll
    for (int mi = 0; mi < 4; mi++)
        #pragma unroll
        for (int ni = 0; ni < 4; ni++)
            #pragma unroll
            for (int i = 0; i < 4; i++) {
                int t = mi * 16 + quad * 4 + i, tp = ni * 16 + lm;
                float pv = (ni < mi) ? accP[mi][ni][i]
                          : (ni == mi ? ((tp <= t) ? accP[mi][ni][i] : 0.f) : 0.f);
                L.r.p[t][tp] = f2bf(pv);
            }
    __syncthreads();

    // ---- Y(b) = P . V ----
    v8bf vb[4][2];
    #pragma unroll
    for (int nd = 0; nd < 4; nd++)
        #pragma unroll
        for (int ki = 0; ki < 2; ki++)
            vb[nd][ki] = *(const v8bf*)&L.VT[nd * 16 + lm][ki * 32 + quad * 8];
    #pragma unroll
    for (int mi = 0; mi < 4; mi++)
        #pragma unroll
        for (int ki = 0; ki < 2; ki++) {
            if (ki == 1 && mi < 2) continue;       // p block all-zero
            v8bf pa = *(const v8bf*)&L.r.p[mi * 16 + lm][ki * 32 + quad * 8];
            #pragma unroll
            for (int nd = 0; nd < 4; nd++)
                accY[mi][nd] = __builtin_amdgcn_mfma_f32_16x16x32_bf16(
                                   pa, vb[nd][ki], accY[mi][nd], 0, 0, 0);
        }

    // ---- store Y:  flat = ((c*64+t)*64 + bh)*64 + d ----
    #pragma unroll
    for (int mi = 0; mi < 4; mi++)
        #pragma unroll
        for (int nd = 0; nd < 4; nd++)
            #pragma unroll
            for (int i = 0; i < 4; i++) {
                int t = mi * 16 + quad * 4 + i;
                Y[(((size_t)(c * 64 + t)) * 64 + bh) * 64 + nd * 16 + lm] =
                    f2bf(accY[mi][nd][i]);
            }
}

// ---------------------------------------------------------------------------
// P4: Z = Y^T :  Y (262144 x 64) -> Z (64 x 262144)
// ---------------------------------------------------------------------------
__global__ __launch_bounds__(64) void transpose_Y(
        const u16* __restrict__ Y, u16* __restrict__ Z)
{
    __shared__ __align__(16) u16 tile[64][72];
    const int g = blockIdx.x;
    const int t = threadIdx.x;
    const u16* yp = Y + ((size_t)(g * 64 + t)) * 64;
    #pragma unroll
    for (int seg = 0; seg < 8; ++seg)
        *(v8u*)&tile[t][seg * 8] = *(const v8u*)(yp + seg * 8);
    __syncthreads();
    const int d = t;
    u16* zp = Z + (size_t)d * 262144 + (size_t)g * 64;
    #pragma unroll
    for (int seg = 0; seg < 8; ++seg) {
        v8u pk;
        #pragma unroll
        for (int j = 0; j < 8; j++) pk[j] = tile[seg * 8 + j][d];
        *(v8u*)(zp + seg * 8) = pk;
    }
}

// ---------------------------------------------------------------------------
extern "C" void kernel_launch(void* const* d_in, const int* in_sizes, int n_in,
                              void* d_out, int out_size, void* d_ws, size_t ws_size,
                              hipStream_t stream)
{
    (void)in_sizes; (void)n_in; (void)out_size; (void)ws_size;
    const float* X  = (const float*)d_in[0];
    const float* Wk = (const float*)d_in[1];   // dict order: X, Wk, Wq, Wv, o_proj
    const float* Wq = (const float*)d_in[2];
    const float* Wv = (const float*)d_in[3];
    const float* Wo = (const float*)d_in[4];
    float* Out = (float*)d_out;

    char* p = (char*)d_ws;
    auto alloc = [&](size_t bytes) { char* r = p; p += (bytes + 255) & ~(size_t)255; return r; };
    u16*   Xb = (u16*)  alloc((size_t)M_ * 512 * 2);
    u16*   WT = (u16*)  alloc((size_t)768 * 512 * 2);
    u16*   OT = (u16*)  alloc((size_t)512 * 512 * 2);
    u16*   V  = (u16*)  alloc((size_t)M_ * 512 * 2);
    float* Mc = (float*)alloc((size_t)4096 * 1024 * 4);   // 16.78 MB
    float* AB = (float*)alloc((size_t)4096 * 16 * 4);     //  0.26 MB
    float* Q  = (float*)alloc((size_t)M_ * 128 * 4);      // 16.78 MB
    u16*   KE = (u16*)  alloc((size_t)M_ * 128 * 2);      // bf16 now
    u16*   Y  = (u16*)  alloc((size_t)M_ * 512 * 2);
    u16*   Z  = (u16*)Mc;  // alias: Mc+AB+Q (33.8MB) dead after intra; Z needs 33.5MB

    f32_to_bf16<<<8192, 256, 0, stream>>>(X, Xb);

    dim3 tb(32, 8);
    transpose_w<<<dim3(4, 16),  tb, 0, stream>>>(Wq, WT + 0   * 512, 512, 128);
    transpose_w<<<dim3(4, 16),  tb, 0, stream>>>(Wk, WT + 128 * 512, 512, 128);
    transpose_w<<<dim3(16, 16), tb, 0, stream>>>(Wv, WT + 256 * 512, 512, 512);
    transpose_w<<<dim3(16, 16), tb, 0, stream>>>(Wo, OT,             512, 512);

    gemm_mfma<0><<<dim3(256, 6), 256, 0, stream>>>(Xb, WT, Q, KE, V, nullptr);
    chunk_sums_mfma<<<1024, 256, 0, stream>>>(KE, V, Mc, AB);
    chunk_prefix   <<<256,  256, 0, stream>>>(Mc, AB);
    intra_mfma     <<<1024, 256, 0, stream>>>(Q, KE, V, Mc, AB, Y);
    transpose_Y    <<<4096, 64,  0, stream>>>(Y, Z);
    gemm_mfma<1><<<dim3(256, 4), 256, 0, stream>>>(Z, OT, nullptr, nullptr, nullptr, Out);
}

// Round 4
// 248.734 us; speedup vs baseline: 2.0511x; 1.1479x over previous
//
#include <hip/hip_runtime.h>
#include <hip/hip_bf16.h>

#define B_ 8
#define T_ 4096
#define D_ 512
#define L_ 128
#define H_ 8
#define Dh_ 64
#define Lh_ 16
#define M_ (B_*T_)          // 32768 rows
#define SCALE 0.125f        // rsqrt(Dh)

typedef __bf16 v8bf __attribute__((ext_vector_type(8)));
typedef float  v4f  __attribute__((ext_vector_type(4)));
typedef unsigned short u16;
typedef u16 v8u __attribute__((ext_vector_type(8)));

__device__ __forceinline__ float b2f(u16 h){
    unsigned int u = ((unsigned int)h) << 16;
    return __builtin_bit_cast(float, u);
}
__device__ __forceinline__ u16 f2bf(float f){
    unsigned int u = __builtin_bit_cast(unsigned int, f);
    u += 0x7FFFu + ((u >> 16) & 1u);   // RNE
    return (u16)(u >> 16);
}

// async global->LDS, 16B per lane; lds dest = wave-uniform base + lane*16
__device__ __forceinline__ void gload16(const u16* g, u16* l) {
    __builtin_amdgcn_global_load_lds(
        (const __attribute__((address_space(1))) unsigned int*)(g),
        (__attribute__((address_space(3))) unsigned int*)(l), 16, 0, 0);
}

// ---------------------------------------------------------------------------
// prep: one launch = X fp32->bf16 convert (blocks 0..8191) + 4 weight
// transposes fp32(rows x cols) -> bf16 (cols x rows) (blocks 8192..8831)
// ---------------------------------------------------------------------------
__global__ __launch_bounds__(256) void prep(
        const float* __restrict__ X,  const float* __restrict__ Wq,
        const float* __restrict__ Wk, const float* __restrict__ Wv,
        const float* __restrict__ Wo,
        u16* __restrict__ Xb, u16* __restrict__ WT, u16* __restrict__ OT)
{
    int bid = blockIdx.x;
    if (bid < 8192) {   // X convert: 8 elems / thread
        const size_t i = (size_t)bid * 256 + threadIdx.x;
        const float4* s = (const float4*)X + i * 2;
        float4 a = s[0], b = s[1];
        v8u o;
        o[0] = f2bf(a.x); o[1] = f2bf(a.y); o[2] = f2bf(a.z); o[3] = f2bf(a.w);
        o[4] = f2bf(b.x); o[5] = f2bf(b.y); o[6] = f2bf(b.z); o[7] = f2bf(b.w);
        *((v8u*)Xb + i) = o;
        return;
    }
    bid -= 8192;
    const float* src; u16* dst; int cols, bx, by;
    if (bid < 64)       { src = Wq; dst = WT;             cols = 128; bx = bid & 3;  by = bid >> 2; }
    else if (bid < 128) { src = Wk; dst = WT + 128 * 512; cols = 128; bid -= 64;  bx = bid & 3;  by = bid >> 2; }
    else if (bid < 384) { src = Wv; dst = WT + 256 * 512; cols = 512; bid -= 128; bx = bid & 15; by = bid >> 4; }
    else                { src = Wo; dst = OT;             cols = 512; bid -= 384; bx = bid & 15; by = bid >> 4; }
    __shared__ u16 tile[32][33];
    const int tx = threadIdx.x & 31, ty = threadIdx.x >> 5;
    const int c0 = bx * 32, r0 = by * 32;
    #pragma unroll
    for (int i = 0; i < 32; i += 8)
        tile[ty + i][tx] = f2bf(src[(size_t)(r0 + ty + i) * cols + c0 + tx]);
    __syncthreads();
    #pragma unroll
    for (int i = 0; i < 32; i += 8)
        dst[(size_t)(c0 + ty + i) * 512 + r0 + tx] = tile[tx][ty + i];
}

// ---------------------------------------------------------------------------
// P1/P5: MFMA bf16 GEMM, m97-style: BK=64, global_load_lds width=16 staging,
// XOR granule swizzle (pos = g ^ (row&7)) so frag reads are 2-way (free).
// MODE 0: write Q(f32) / KE=exp(K*s)(bf16) / V(bf16).  MODE 1: fp32 Out.
// ---------------------------------------------------------------------------
template<int MODE>
__global__ __launch_bounds__(256) void gemm_mfma(
        const u16* __restrict__ A, const u16* __restrict__ Bt,
        float* __restrict__ Qo, u16* __restrict__ KEo,
        u16* __restrict__ Vo, float* __restrict__ OutF)
{
    __shared__ __align__(16) u16 As[128 * 64];   // row*64 + (g^(row&7))*8
    __shared__ __align__(16) u16 Bs[128 * 64];
    const int tid  = threadIdx.x;
    const int wave = tid >> 6, lane = tid & 63;
    const int wm = wave >> 1, wn = wave & 1;     // 2x2 waves, 64x64 each
    const int lm = lane & 15, quad = lane >> 4;
    const int gm0 = blockIdx.x * 128, gn0 = blockIdx.y * 128;

    const int srow0 = wave * 32 + (lane >> 3);   // staging row, + r*8
    const int sg    = lane & 7;                  // staging granule position

    v4f acc[4][4];
    #pragma unroll
    for (int i = 0; i < 4; i++)
        #pragma unroll
        for (int j = 0; j < 4; j++)
            acc[i][j] = (v4f){0.f, 0.f, 0.f, 0.f};

    for (int kt = 0; kt < 8; ++kt) {
        const int k0 = kt * 64;
        #pragma unroll
        for (int r = 0; r < 4; ++r) {
            const int row = srow0 + r * 8;
            const int col = ((sg ^ (row & 7)) << 3) + k0;   // source k-granule
            gload16(&A [(size_t)(gm0 + row) * 512 + col], &As[(wave * 4 + r) * 512]);
            gload16(&Bt[(size_t)(gn0 + row) * 512 + col], &Bs[(wave * 4 + r) * 512]);
        }
        __syncthreads();
        v8bf af[2][4], bfr[2][4];
        #pragma unroll
        for (int ks = 0; ks < 2; ks++)
            #pragma unroll
            for (int mi = 0; mi < 4; mi++) {
                const int g  = ks * 4 + quad;
                const int ra = wm * 64 + mi * 16 + lm;
                const int rb = wn * 64 + mi * 16 + lm;
                af [ks][mi] = *(const v8bf*)&As[ra * 64 + ((g ^ (ra & 7)) << 3)];
                bfr[ks][mi] = *(const v8bf*)&Bs[rb * 64 + ((g ^ (rb & 7)) << 3)];
            }
        #pragma unroll
        for (int ks = 0; ks < 2; ks++)
            #pragma unroll
            for (int mi = 0; mi < 4; mi++)
                #pragma unroll
                for (int ni = 0; ni < 4; ni++)
                    acc[mi][ni] = __builtin_amdgcn_mfma_f32_16x16x32_bf16(
                                      af[ks][mi], bfr[ks][ni], acc[mi][ni], 0, 0, 0);
        __syncthreads();
    }

    #pragma unroll
    for (int mi = 0; mi < 4; mi++)
      #pragma unroll
      for (int ni = 0; ni < 4; ni++)
        #pragma unroll
        for (int i = 0; i < 4; i++) {
            int row = gm0 + wm * 64 + mi * 16 + quad * 4 + i;  // C/D: row=quad*4+reg
            int col = gn0 + wn * 64 + ni * 16 + lm;            //      col=lane&15
            float v = acc[mi][ni][i];
            if (MODE == 0) {
                if (col < 128)        Qo [(size_t)row * 128 + col]       = v;
                else if (col < 256)   KEo[(size_t)row * 128 + col - 128] = f2bf(__expf(v * SCALE));
                else                  Vo [(size_t)row * 512 + col - 256] = f2bf(v);
            } else {
                OutF[(size_t)row * 512 + col] = v;
            }
        }
}

// ---------------------------------------------------------------------------
// P2a (MFMA): per chunk, one wave: M_c = KE^T(16x64) . V(64x64), lsum = KE^T . 1
// ---------------------------------------------------------------------------
__global__ __launch_bounds__(256, 2) void chunk_sums_mfma(
        const u16* __restrict__ KE, const u16* __restrict__ V,
        float* __restrict__ Mc, float* __restrict__ AB)
{
    struct CLDS { u16 KA[16][72]; u16 VT[64][72]; };
    __shared__ __align__(16) CLDS lds[4];
    const int tid = threadIdx.x, wave = tid >> 6, lane = tid & 63;
    const int lm = lane & 15, quad = lane >> 4;
    const int ch = blockIdx.x * 4 + wave;
    const int bh = ch >> 6, c = ch & 63, b = bh >> 3, h = bh & 7;
    const int t0 = b * T_ + c * 64;
    CLDS& L = lds[wave];

    {
        const u16* kp = KE + (size_t)(t0 + lane) * L_ + h * Lh_;
        v8u k0 = *(const v8u*)kp, k1 = *(const v8u*)(kp + 8);
        #pragma unroll
        for (int l = 0; l < 8; l++) L.KA[l][lane]     = k0[l];
        #pragma unroll
        for (int l = 0; l < 8; l++) L.KA[l + 8][lane] = k1[l];
        const u16* vp = V + (size_t)(t0 + lane) * D_ + h * Dh_;
        #pragma unroll
        for (int seg = 0; seg < 8; ++seg) {
            v8u pv = *(const v8u*)(vp + seg * 8);
            #pragma unroll
            for (int j = 0; j < 8; j++) L.VT[seg * 8 + j][lane] = pv[j];
        }
    }
    __syncthreads();

    v8bf ka[2];
    #pragma unroll
    for (int ki = 0; ki < 2; ki++)
        ka[ki] = *(const v8bf*)&L.KA[lm][ki * 32 + quad * 8];

    v8u onesu;
    #pragma unroll
    for (int j = 0; j < 8; j++) onesu[j] = 0x3F80;
    v8bf ones = __builtin_bit_cast(v8bf, onesu);

    v4f accL = (v4f){0.f, 0.f, 0.f, 0.f};
    accL = __builtin_amdgcn_mfma_f32_16x16x32_bf16(ka[0], ones, accL, 0, 0, 0);
    accL = __builtin_amdgcn_mfma_f32_16x16x32_bf16(ka[1], ones, accL, 0, 0, 0);

    v4f accM[4];
    #pragma unroll
    for (int nd = 0; nd < 4; nd++) accM[nd] = (v4f){0.f, 0.f, 0.f, 0.f};
    #pragma unroll
    for (int nd = 0; nd < 4; nd++)
        #pragma unroll
        for (int ki = 0; ki < 2; ki++) {
            v8bf vb = *(const v8bf*)&L.VT[nd * 16 + lm][ki * 32 + quad * 8];
            accM[nd] = __builtin_amdgcn_mfma_f32_16x16x32_bf16(ka[ki], vb, accM[nd], 0, 0, 0);
        }

    float* mcb = Mc + (size_t)ch * 1024;
    #pragma unroll
    for (int nd = 0; nd < 4; nd++)
        #pragma unroll
        for (int i = 0; i < 4; i++)
            mcb[(quad * 4 + i) * 64 + nd * 16 + lm] = accM[nd][i];
    if (lm == 0) {
        #pragma unroll
        for (int i = 0; i < 4; i++) AB[ch * 16 + quad * 4 + i] = accL[i];
    }
}

// ---------------------------------------------------------------------------
// P2b: exclusive prefix over chunks (in-place).  256 blocks x 256 threads.
// ---------------------------------------------------------------------------
__global__ __launch_bounds__(256) void chunk_prefix(
        float* __restrict__ Mc, float* __restrict__ AB)
{
    const int bh = blockIdx.x >> 2, qq = blockIdx.x & 3;
    const int i = qq * 256 + threadIdx.x;
    float run = 0.f;
    for (int c = 0; c < 64; ++c) {
        size_t off = ((size_t)(bh * 64 + c)) * 1024 + i;
        float m = Mc[off]; Mc[off] = run; run += m;
    }
    if (qq == 0 && threadIdx.x < 16) {
        float r2 = 0.f; const int l = threadIdx.x;
        for (int c = 0; c < 64; ++c) {
            int off = (bh * 64 + c) * 16 + l;
            float a = AB[off]; AB[off] = r2; r2 += a;
        }
    }
}

// ---------------------------------------------------------------------------
// P3 (MFMA): alpha = AB + tril.ke; qs = softmax(q*s)/alpha;
// P = QS.KE^T (masked); Y = QS.S_c + P.V
// ---------------------------------------------------------------------------
__global__ __launch_bounds__(256, 2) void intra_mfma(
        const float* __restrict__ Q, const u16* __restrict__ KE,
        const u16* __restrict__ V, const float* __restrict__ Mc,
        const float* __restrict__ AB, u16* __restrict__ Y)
{
    struct ILDS {
        union {
            struct { u16 KA[16][72]; u16 Sc[16][72]; u16 qs[64][40]; } s;
            u16 p[64][72];
        } r;
        u16 VT[64][72];
    };
    __shared__ __align__(16) ILDS lds[4];
    const int tid = threadIdx.x, wave = tid >> 6, lane = tid & 63;
    const int lm = lane & 15, quad = lane >> 4;
    const int ch = blockIdx.x * 4 + wave;
    const int bh = ch >> 6, c = ch & 63, b = bh >> 3, h = bh & 7;
    const int t0 = b * T_ + c * 64;
    ILDS& L = lds[wave];

    {
        const u16* kp = KE + (size_t)(t0 + lane) * L_ + h * Lh_;
        v8u k0 = *(const v8u*)kp, k1 = *(const v8u*)(kp + 8);
        #pragma unroll
        for (int l = 0; l < 8; l++) L.r.s.KA[l][lane]     = k0[l];
        #pragma unroll
        for (int l = 0; l < 8; l++) L.r.s.KA[l + 8][lane] = k1[l];
        const u16* vp = V + (size_t)(t0 + lane) * D_ + h * Dh_;
        #pragma unroll
        for (int seg = 0; seg < 8; ++seg) {
            v8u pv = *(const v8u*)(vp + seg * 8);
            #pragma unroll
            for (int j = 0; j < 8; j++) L.VT[seg * 8 + j][lane] = pv[j];
        }
        const float* mcb = Mc + (size_t)ch * 1024;
        #pragma unroll
        for (int l = 0; l < 16; l++)
            L.r.s.Sc[l][lane] = f2bf(mcb[l * 64 + lane]);
        v8u z8;
        #pragma unroll
        for (int j = 0; j < 8; j++) z8[j] = 0;
        *(v8u*)&L.r.s.qs[lane][16] = z8;
        *(v8u*)&L.r.s.qs[lane][24] = z8;
    }
    const float ab = AB[ch * 16 + lm];
    __syncthreads();

    v4f acc_a[4];
    #pragma unroll
    for (int mi = 0; mi < 4; mi++) acc_a[mi] = (v4f){ab, ab, ab, ab};
    #pragma unroll
    for (int mi = 0; mi < 4; mi++)
        #pragma unroll
        for (int ki = 0; ki < 2; ki++) {
            if (ki == 1 && mi < 2) continue;
            v8u ta;
            #pragma unroll
            for (int j = 0; j < 8; j++)
                ta[j] = (ki * 32 + quad * 8 + j <= mi * 16 + lm) ? (u16)0x3F80 : (u16)0;
            v8bf kb = *(const v8bf*)&L.r.s.KA[lm][ki * 32 + quad * 8];
            acc_a[mi] = __builtin_amdgcn_mfma_f32_16x16x32_bf16(
                            __builtin_bit_cast(v8bf, ta), kb, acc_a[mi], 0, 0, 0);
        }

    #pragma unroll
    for (int mi = 0; mi < 4; mi++)
        #pragma unroll
        for (int i = 0; i < 4; i++) {
            int t = mi * 16 + quad * 4 + i;
            float qv = Q[(size_t)(t0 + t) * L_ + h * Lh_ + lm] * SCALE;
            float m = qv;
            #pragma unroll
            for (int off = 1; off < 16; off <<= 1) m = fmaxf(m, __shfl_xor(m, off));
            float e = __expf(qv - m);
            float s = e;
            #pragma unroll
            for (int off = 1; off < 16; off <<= 1) s += __shfl_xor(s, off);
            L.r.s.qs[t][lm] = f2bf(e / (s * acc_a[mi][i]));
        }
    __syncthreads();

    v8bf aq[4];
    #pragma unroll
    for (int mi = 0; mi < 4; mi++)
        aq[mi] = *(const v8bf*)&L.r.s.qs[mi * 16 + lm][quad * 8];

    v4f accP[4][4], accY[4][4];
    #pragma unroll
    for (int mi = 0; mi < 4; mi++)
        #pragma unroll
        for (int ni = 0; ni < 4; ni++) {
            accP[mi][ni] = (v4f){0.f, 0.f, 0.f, 0.f};
            accY[mi][ni] = (v4f){0.f, 0.f, 0.f, 0.f};
        }

    #pragma unroll
    for (int ni = 0; ni < 4; ni++) {
        v8u kbu;
        #pragma unroll
        for (int j = 0; j < 8; j++) kbu[j] = 0;
        if (quad < 2) {
            #pragma unroll
            for (int j = 0; j < 8; j++)
                kbu[j] = L.r.s.KA[quad * 8 + j][ni * 16 + lm];
        }
        v8bf kbf = __builtin_bit_cast(v8bf, kbu);
        #pragma unroll
        for (int mi = ni; mi < 4; mi++)
            accP[mi][ni] = __builtin_amdgcn_mfma_f32_16x16x32_bf16(
                               aq[mi], kbf, accP[mi][ni], 0, 0, 0);
    }
    #pragma unroll
    for (int nd = 0; nd < 4; nd++) {
        v8u scu;
        #pragma unroll
        for (int j = 0; j < 8; j++) scu[j] = 0;
        if (quad < 2) {
            #pragma unroll
            for (int j = 0; j < 8; j++)
                scu[j] = L.r.s.Sc[quad * 8 + j][nd * 16 + lm];
        }
        v8bf scf = __builtin_bit_cast(v8bf, scu);
        #pragma unroll
        for (int mi = 0; mi < 4; mi++)
            accY[mi][nd] = __builtin_amdgcn_mfma_f32_16x16x32_bf16(
                               aq[mi], scf, accY[mi][nd], 0, 0, 0);
    }
    __syncthreads();

    #pragma unroll
    for (int mi = 0; mi < 4; mi++)
        #pragma unroll
        for (int ni = 0; ni < 4; ni++)
            #pragma unroll
            for (int i = 0; i < 4; i++) {
                int t = mi * 16 + quad * 4 + i, tp = ni * 16 + lm;
                float pv = (ni < mi) ? accP[mi][ni][i]
                          : (ni == mi ? ((tp <= t) ? accP[mi][ni][i] : 0.f) : 0.f);
                L.r.p[t][tp] = f2bf(pv);
            }
    __syncthreads();

    v8bf vb[4][2];
    #pragma unroll
    for (int nd = 0; nd < 4; nd++)
        #pragma unroll
        for (int ki = 0; ki < 2; ki++)
            vb[nd][ki] = *(const v8bf*)&L.VT[nd * 16 + lm][ki * 32 + quad * 8];
    #pragma unroll
    for (int mi = 0; mi < 4; mi++)
        #pragma unroll
        for (int ki = 0; ki < 2; ki++) {
            if (ki == 1 && mi < 2) continue;
            v8bf pa = *(const v8bf*)&L.r.p[mi * 16 + lm][ki * 32 + quad * 8];
            #pragma unroll
            for (int nd = 0; nd < 4; nd++)
                accY[mi][nd] = __builtin_amdgcn_mfma_f32_16x16x32_bf16(
                                   pa, vb[nd][ki], accY[mi][nd], 0, 0, 0);
        }

    #pragma unroll
    for (int mi = 0; mi < 4; mi++)
        #pragma unroll
        for (int nd = 0; nd < 4; nd++)
            #pragma unroll
            for (int i = 0; i < 4; i++) {
                int t = mi * 16 + quad * 4 + i;
                Y[(((size_t)(c * 64 + t)) * 64 + bh) * 64 + nd * 16 + lm] =
                    f2bf(accY[mi][nd][i]);
            }
}

// ---------------------------------------------------------------------------
// P4: Z = Y^T :  Y (262144 x 64) -> Z (64 x 262144).  Both sides coalesced:
// write pass p covers 8 Z-rows; 8 lanes cover 128B contiguous per store.
// ---------------------------------------------------------------------------
__global__ __launch_bounds__(64) void transpose_Y(
        const u16* __restrict__ Y, u16* __restrict__ Z)
{
    __shared__ __align__(16) u16 tile[64][72];
    const int g = blockIdx.x, t = threadIdx.x;
    const u16* yp = Y + (size_t)(g * 64 + t) * 64;
    #pragma unroll
    for (int seg = 0; seg < 8; ++seg)
        *(v8u*)&tile[t][seg * 8] = *(const v8u*)(yp + seg * 8);
    __syncthreads();
    const int cl = t & 7, dq = t >> 3;
    #pragma unroll
    for (int p = 0; p < 8; ++p) {
        const int dh = p * 8 + dq;
        v8u pk;
        #pragma unroll
        for (int j = 0; j < 8; j++) pk[j] = tile[cl * 8 + j][dh];
        *(v8u*)&Z[(size_t)dh * 262144 + (size_t)g * 64 + cl * 8] = pk;
    }
}

// ---------------------------------------------------------------------------
extern "C" void kernel_launch(void* const* d_in, const int* in_sizes, int n_in,
                              void* d_out, int out_size, void* d_ws, size_t ws_size,
                              hipStream_t stream)
{
    (void)in_sizes; (void)n_in; (void)out_size; (void)ws_size;
    const float* X  = (const float*)d_in[0];
    const float* Wk = (const float*)d_in[1];   // dict order: X, Wk, Wq, Wv, o_proj
    const float* Wq = (const float*)d_in[2];
    const float* Wv = (const float*)d_in[3];
    const float* Wo = (const float*)d_in[4];
    float* Out = (float*)d_out;

    char* p = (char*)d_ws;
    auto alloc = [&](size_t bytes) { char* r = p; p += (bytes + 255) & ~(size_t)255; return r; };
    u16*   Xb = (u16*)  alloc((size_t)M_ * 512 * 2);
    u16*   WT = (u16*)  alloc((size_t)768 * 512 * 2);
    u16*   OT = (u16*)  alloc((size_t)512 * 512 * 2);
    u16*   V  = (u16*)  alloc((size_t)M_ * 512 * 2);
    float* Mc = (float*)alloc((size_t)4096 * 1024 * 4);   // 16.78 MB
    float* AB = (float*)alloc((size_t)4096 * 16 * 4);
    float* Q  = (float*)alloc((size_t)M_ * 128 * 4);      // 16.78 MB
    u16*   KE = (u16*)  alloc((size_t)M_ * 128 * 2);
    u16*   Y  = (u16*)  alloc((size_t)M_ * 512 * 2);
    u16*   Z  = (u16*)Mc;  // alias: Mc+AB+Q (33.8MB) dead after intra; Z needs 33.5MB

    prep<<<8832, 256, 0, stream>>>(X, Wq, Wk, Wv, Wo, Xb, WT, OT);

    gemm_mfma<0><<<dim3(256, 6), 256, 0, stream>>>(Xb, WT, Q, KE, V, nullptr);
    chunk_sums_mfma<<<1024, 256, 0, stream>>>(KE, V, Mc, AB);
    chunk_prefix   <<<256,  256, 0, stream>>>(Mc, AB);
    intra_mfma     <<<1024, 256, 0, stream>>>(Q, KE, V, Mc, AB, Y);
    transpose_Y    <<<4096, 64,  0, stream>>>(Y, Z);
    gemm_mfma<1><<<dim3(256, 4), 256, 0, stream>>>(Z, OT, nullptr, nullptr, nullptr, Out);
}